// Round 1
// baseline (268.131 us; speedup 1.0000x reference)
//
#include <hip/hip_runtime.h>
#include <math.h>

// Problem constants (match reference setup_inputs)
#define Hc 96
#define Wc 96
#define Bc 2
#define Cc 256            // channels
#define HWc (Hc * Wc)     // 9216
#define NKc 25            // 5x5 neighborhood
#define CENTERc 12
#define NPIX (Bc * HWc)   // 18432

__device__ __forceinline__ float wave_reduce_sum(float v) {
#pragma unroll
  for (int off = 32; off > 0; off >>= 1) v += __shfl_xor(v, off);
  return v;
}

// ---------------------------------------------------------------
// 1) Transpose er_input [B,C,HW] -> featT [B,HW,C]  (LDS tiled)
// ---------------------------------------------------------------
__global__ __launch_bounds__(256) void transpose_kernel(
    const float* __restrict__ in, float* __restrict__ out) {
  __shared__ float tile[32][33];
  const int bx = blockIdx.x;  // HW/32 = 288
  const int by = blockIdx.y;  // C/32  = 8
  const int b = blockIdx.z;
  const float* src = in + (size_t)b * Cc * HWc;
  float* dst = out + (size_t)b * HWc * Cc;
  const int tx = threadIdx.x;  // 0..31
  const int ty = threadIdx.y;  // 0..7
  const int p0 = bx * 32, c0 = by * 32;
#pragma unroll
  for (int i = 0; i < 4; i++)
    tile[ty + i * 8][tx] = src[(size_t)(c0 + ty + i * 8) * HWc + p0 + tx];
  __syncthreads();
#pragma unroll
  for (int i = 0; i < 4; i++)
    dst[(size_t)(p0 + ty + i * 8) * Cc + c0 + tx] = tile[tx][ty + i * 8];
}

// ---------------------------------------------------------------
// 2) Per-pixel L2 norm + argmax(pred).  One wave per pixel.
// ---------------------------------------------------------------
__global__ __launch_bounds__(256) void prep_kernel(
    const float* __restrict__ featT, const float* __restrict__ seg_logit,
    float* __restrict__ nrm, int* __restrict__ pred) {
  const int wid = (blockIdx.x * 256 + threadIdx.x) >> 6;
  const int lane = threadIdx.x & 63;
  if (wid >= NPIX) return;
  float4 f = ((const float4*)featT)[(size_t)wid * 64 + lane];
  float s = wave_reduce_sum(f.x * f.x + f.y * f.y + f.z * f.z + f.w * f.w);
  if (lane == 0) {
    nrm[wid] = sqrtf(s);
    const int b = wid / HWc, hw = wid % HWc;
    const float l0 = seg_logit[(size_t)(b * 2 + 0) * HWc + hw];
    const float l1 = seg_logit[(size_t)(b * 2 + 1) * HWc + hw];
    pred[wid] = (l1 > l0) ? 1 : 0;  // argmax (first index on tie)
  }
}

// ---------------------------------------------------------------
// 3) Main loss kernel.  One wave per pixel.
//    accum layout: [loss_c0, cnt_c0, loss_c1, cnt_c1]
// ---------------------------------------------------------------
__global__ __launch_bounds__(256) void loss_kernel(
    const float* __restrict__ featT, const float* __restrict__ nrm,
    const int* __restrict__ pred, const int* __restrict__ label,
    const int* __restrict__ gtb, float* __restrict__ accum) {
  const int wid = (blockIdx.x * 256 + threadIdx.x) >> 6;
  const int lane = threadIdx.x & 63;
  if (wid >= NPIX) return;
  const int b = wid / HWc, hw = wid % HWc;
  const int h = hw / Wc, w = hw % Wc;

  int g = gtb[wid];
  if (g == 255) g = 0;
  if (g == 0) return;  // not on boundary: pix_mask = 0 for both classes

  const int c = label[wid];
  const int oc = 1 - c;

  // lanes 0..24 fetch neighbor metadata (zero-pad: OOB -> label 0, pred 0, norm 0)
  int offk = -1, lblk = 0, prdk = 0;
  float nrmk = 0.f;
  if (lane < NKc) {
    const int di = lane / 5 - 2, dj = lane % 5 - 2;
    const int hh = h + di, ww = w + dj;
    if (hh >= 0 && hh < Hc && ww >= 0 && ww < Wc) {
      const int n = b * HWc + hh * Wc + ww;
      offk = n;
      lblk = label[n];
      prdk = pred[n];
      nrmk = nrm[n];
    }
  }

  // same-class neighbor count, center excluded (zero-pad labels count for c==0)
  const bool is_c = (lane < NKc) && (lblk == c);
  const unsigned long long m_ballot = __ballot(is_c);
  const int count = __popcll(m_ballot) - 1;  // center always matches c
  if (count < 1) return;                     // pix_mask = 0

  // pixel contributes: pix_mask = 1 for class c
  const int pc = pred[wid];
  float loss;
  if (pc != c) {
    // anchor = 0 -> every logit is exactly 0 -> uniform softmax over 26
    loss = logf(26.0f);
  } else {
    const float4* fp = (const float4*)featT;
    const float4 anchor = fp[(size_t)wid * 64 + lane];
    const float a_norm = nrm[wid];

    float4 pos = make_float4(0.f, 0.f, 0.f, 0.f);
    float dpart[NKc];
#pragma unroll
    for (int k = 0; k < NKc; k++) {
      const int off = __shfl(offk, k);
      const int lb = __shfl(lblk, k);
      const int pr = __shfl(prdk, k);
      float4 f = make_float4(0.f, 0.f, 0.f, 0.f);
      if (off >= 0) f = fp[(size_t)off * 64 + lane];
      if ((lb == c) && (pr == c)) {
        pos.x += f.x; pos.y += f.y; pos.z += f.z; pos.w += f.w;
      }
      dpart[k] = anchor.x * f.x + anchor.y * f.y + anchor.z * f.z + anchor.w * f.w;
    }
    // positive = (sum - anchor)/25  (center is "correct" here, so it was summed)
    float4 pv;
    pv.x = (pos.x - anchor.x) * (1.0f / 25.0f);
    pv.y = (pos.y - anchor.y) * (1.0f / 25.0f);
    pv.z = (pos.z - anchor.z) * (1.0f / 25.0f);
    pv.w = (pos.w - anchor.w) * (1.0f / 25.0f);

    const float p2 = wave_reduce_sum(pv.x * pv.x + pv.y * pv.y + pv.z * pv.z + pv.w * pv.w);
    const float ad = wave_reduce_sum(anchor.x * pv.x + anchor.y * pv.y +
                                     anchor.z * pv.z + anchor.w * pv.w);
    const float p_norm = sqrtf(p2);
    const float pos_cos = ad / (a_norm * p_norm + 1e-8f);

    float xs[NKc + 1];
    xs[0] = pos_cos / 0.1f;
#pragma unroll
    for (int k = 0; k < NKc; k++) {
      const int lb = __shfl(lblk, k);
      const int pr = __shfl(prdk, k);
      const float nk = __shfl(nrmk, k);
      float ncos = 0.f;
      if ((lb == oc) && (pr == oc)) {  // wave-uniform branch
        const float d = wave_reduce_sum(dpart[k]);
        ncos = (d * 2.0f) / (a_norm * nk * 2.0f + 1e-8f);
      }
      xs[k + 1] = ncos / 0.1f;
    }
    float mx = xs[0];
#pragma unroll
    for (int k = 1; k <= NKc; k++) mx = fmaxf(mx, xs[k]);
    float s = 0.f;
#pragma unroll
    for (int k = 0; k <= NKc; k++) s += expf(xs[k] - mx);
    loss = mx + logf(s) - xs[0];
  }

  if (lane == 0) {
    atomicAdd(accum + 2 * c + 0, loss);
    atomicAdd(accum + 2 * c + 1, 1.0f);
  }
}

// ---------------------------------------------------------------
// 4) Finalize: total = sum_c loss_c / max(cnt_c, 1)
// ---------------------------------------------------------------
__global__ void finalize_kernel(const float* __restrict__ accum,
                                float* __restrict__ out) {
  out[0] = accum[0] / fmaxf(accum[1], 1.0f) + accum[2] / fmaxf(accum[3], 1.0f);
}

extern "C" void kernel_launch(void* const* d_in, const int* in_sizes, int n_in,
                              void* d_out, int out_size, void* d_ws, size_t ws_size,
                              hipStream_t stream) {
  const float* er = (const float*)d_in[0];         // [B,C,H,W]
  const float* seg_logit = (const float*)d_in[1];  // [B,2,H,W]
  const int* seg_label = (const int*)d_in[2];      // [B,H,W]
  const int* gtb = (const int*)d_in[3];            // [B,H,W]
  float* out = (float*)d_out;

  // Workspace layout
  char* ws = (char*)d_ws;
  float* accum = (float*)ws;                    // 4 floats (zeroed below)
  int* pred = (int*)(ws + 64);                  // NPIX ints
  float* nrm = (float*)(ws + 64 + NPIX * 4);    // NPIX floats
  float* featT = (float*)(ws + 64 + NPIX * 8);  // NPIX * C floats (~18.9 MB)

  hipMemsetAsync(d_ws, 0, 64, stream);

  dim3 tb(32, 8, 1);
  dim3 tg(HWc / 32, Cc / 32, Bc);  // 288 x 8 x 2
  transpose_kernel<<<tg, tb, 0, stream>>>(er, featT);

  const int nblocks = (NPIX * 64) / 256;  // 4608, one wave per pixel
  prep_kernel<<<nblocks, 256, 0, stream>>>(featT, seg_logit, nrm, pred);
  loss_kernel<<<nblocks, 256, 0, stream>>>(featT, nrm, pred, seg_label, gtb, accum);
  finalize_kernel<<<1, 1, 0, stream>>>(accum, out);
}

// Round 2
// 94.360 us; speedup vs baseline: 2.8416x; 2.8416x over previous
//
#include <hip/hip_runtime.h>
#include <math.h>

// Problem constants (match reference setup_inputs)
#define Hc 96
#define Wc 96
#define Bc 2
#define Cc 256            // channels
#define HWc (Hc * Wc)     // 9216
#define NKc 25            // 5x5 neighborhood
#define NPIX (Bc * HWc)   // 18432
#define NSLOT 64          // spread accumulation slots (atomic decontention)

__device__ __forceinline__ float wave_reduce_sum(float v) {
#pragma unroll
  for (int off = 32; off > 0; off >>= 1) v += __shfl_xor(v, off);
  return v;
}

// ---------------------------------------------------------------
// 1) Transpose er_input [B,C,HW] -> featT [B,HW,C]  (LDS tiled)
// ---------------------------------------------------------------
__global__ __launch_bounds__(256) void transpose_kernel(
    const float* __restrict__ in, float* __restrict__ out) {
  __shared__ float tile[32][33];
  const int bx = blockIdx.x;  // HW/32 = 288
  const int by = blockIdx.y;  // C/32  = 8
  const int b = blockIdx.z;
  const float* src = in + (size_t)b * Cc * HWc;
  float* dst = out + (size_t)b * HWc * Cc;
  const int tx = threadIdx.x;  // 0..31
  const int ty = threadIdx.y;  // 0..7
  const int p0 = bx * 32, c0 = by * 32;
#pragma unroll
  for (int i = 0; i < 4; i++)
    tile[ty + i * 8][tx] = src[(size_t)(c0 + ty + i * 8) * HWc + p0 + tx];
  __syncthreads();
#pragma unroll
  for (int i = 0; i < 4; i++)
    dst[(size_t)(p0 + ty + i * 8) * Cc + c0 + tx] = tile[tx][ty + i * 8];
}

// ---------------------------------------------------------------
// 2) Per-pixel L2 norm + argmax(pred).  One wave per pixel.
// ---------------------------------------------------------------
__global__ __launch_bounds__(256) void prep_kernel(
    const float* __restrict__ featT, const float* __restrict__ seg_logit,
    float* __restrict__ nrm, int* __restrict__ pred) {
  const int wid = (blockIdx.x * 256 + threadIdx.x) >> 6;
  const int lane = threadIdx.x & 63;
  if (wid >= NPIX) return;
  float4 f = ((const float4*)featT)[(size_t)wid * 64 + lane];
  float s = wave_reduce_sum(f.x * f.x + f.y * f.y + f.z * f.z + f.w * f.w);
  if (lane == 0) {
    nrm[wid] = sqrtf(s);
    const int b = wid / HWc, hw = wid % HWc;
    const float l0 = seg_logit[(size_t)(b * 2 + 0) * HWc + hw];
    const float l1 = seg_logit[(size_t)(b * 2 + 1) * HWc + hw];
    pred[wid] = (l1 > l0) ? 1 : 0;  // argmax (first index on tie)
  }
}

// ---------------------------------------------------------------
// 3) Main loss kernel.  One wave per pixel; block-level LDS
//    reduction then ONE atomic pair per block into spread slots.
//    accum layout: NSLOT x [loss_c0, cnt_c0, loss_c1, cnt_c1]
// ---------------------------------------------------------------
__global__ __launch_bounds__(256) void loss_kernel(
    const float* __restrict__ featT, const float* __restrict__ nrm,
    const int* __restrict__ pred, const int* __restrict__ label,
    const int* __restrict__ gtb, float* __restrict__ accum) {
  __shared__ float s_loss[4];
  __shared__ int s_cls[4];
  const int wv = threadIdx.x >> 6;
  const int lane = threadIdx.x & 63;
  const int wid = blockIdx.x * 4 + wv;
  if (lane == 0) {
    s_cls[wv] = -1;
    s_loss[wv] = 0.f;
  }

  // ---- predicated per-wave computation (no early returns) ----
  bool contrib = false;
  float loss = 0.f;
  int c = 0;
  if (wid < NPIX) {
    const int b = wid / HWc, hw = wid % HWc;
    const int h = hw / Wc, w = hw % Wc;
    int g = gtb[wid];
    if (g == 255) g = 0;
    if (g != 0) {  // boundary pixel (wave-uniform branch)
      c = label[wid];
      const int oc = 1 - c;

      // lanes 0..24: neighbor metadata (zero-pad: OOB -> label 0, pred 0, norm 0)
      int offk = -1, lblk = 0, prdk = 0;
      float nrmk = 0.f;
      if (lane < NKc) {
        const int di = lane / 5 - 2, dj = lane % 5 - 2;
        const int hh = h + di, ww = w + dj;
        if (hh >= 0 && hh < Hc && ww >= 0 && ww < Wc) {
          const int n = b * HWc + hh * Wc + ww;
          offk = n;
          lblk = label[n];
          prdk = pred[n];
          nrmk = nrm[n];
        }
      }

      const bool is_c = (lane < NKc) && (lblk == c);
      const int count = __popcll(__ballot(is_c)) - 1;  // center excluded
      if (count >= 1) {
        contrib = true;
        const int pc = pred[wid];
        if (pc != c) {
          // anchor = 0 -> all 26 logits exactly 0 -> uniform softmax
          loss = logf(26.0f);
        } else {
          const float4* fp = (const float4*)featT;
          const float4 anchor = fp[(size_t)wid * 64 + lane];
          const float a_norm = nrm[wid];

          float4 pos = make_float4(0.f, 0.f, 0.f, 0.f);
          float dpart[NKc];
#pragma unroll
          for (int k = 0; k < NKc; k++) {
            const int off = __shfl(offk, k);
            const int lb = __shfl(lblk, k);
            const int pr = __shfl(prdk, k);
            float4 f = make_float4(0.f, 0.f, 0.f, 0.f);
            if (off >= 0) f = fp[(size_t)off * 64 + lane];
            if ((lb == c) && (pr == c)) {
              pos.x += f.x; pos.y += f.y; pos.z += f.z; pos.w += f.w;
            }
            dpart[k] = anchor.x * f.x + anchor.y * f.y + anchor.z * f.z + anchor.w * f.w;
          }
          float4 pv;
          pv.x = (pos.x - anchor.x) * (1.0f / 25.0f);
          pv.y = (pos.y - anchor.y) * (1.0f / 25.0f);
          pv.z = (pos.z - anchor.z) * (1.0f / 25.0f);
          pv.w = (pos.w - anchor.w) * (1.0f / 25.0f);

          const float p2 = wave_reduce_sum(pv.x * pv.x + pv.y * pv.y +
                                           pv.z * pv.z + pv.w * pv.w);
          const float ad = wave_reduce_sum(anchor.x * pv.x + anchor.y * pv.y +
                                           anchor.z * pv.z + anchor.w * pv.w);
          const float pos_cos = ad / (a_norm * sqrtf(p2) + 1e-8f);

          float xs[NKc + 1];
          xs[0] = pos_cos * 10.0f;
#pragma unroll
          for (int k = 0; k < NKc; k++) {
            const int lb = __shfl(lblk, k);
            const int pr = __shfl(prdk, k);
            const float nk = __shfl(nrmk, k);
            float ncos = 0.f;
            if ((lb == oc) && (pr == oc)) {  // wave-uniform branch
              const float d = wave_reduce_sum(dpart[k]);
              ncos = (d * 2.0f) / (a_norm * nk * 2.0f + 1e-8f);
            }
            xs[k + 1] = ncos * 10.0f;
          }
          float mx = xs[0];
#pragma unroll
          for (int k = 1; k <= NKc; k++) mx = fmaxf(mx, xs[k]);
          float s = 0.f;
#pragma unroll
          for (int k = 0; k <= NKc; k++) s += expf(xs[k] - mx);
          loss = mx + logf(s) - xs[0];
        }
      }
    }
  }

  if (contrib && lane == 0) {
    s_loss[wv] = loss;
    s_cls[wv] = c;
  }
  __syncthreads();

  // one thread per block: combine 4 waves, 2 atomic pairs max into spread slot
  if (threadIdx.x == 0) {
    float l0 = 0.f, n0 = 0.f, l1 = 0.f, n1 = 0.f;
#pragma unroll
    for (int i = 0; i < 4; i++) {
      if (s_cls[i] == 0) { l0 += s_loss[i]; n0 += 1.f; }
      else if (s_cls[i] == 1) { l1 += s_loss[i]; n1 += 1.f; }
    }
    float* slot = accum + (size_t)(blockIdx.x & (NSLOT - 1)) * 4;
    if (n0 > 0.f) { atomicAdd(slot + 0, l0); atomicAdd(slot + 1, n0); }
    if (n1 > 0.f) { atomicAdd(slot + 2, l1); atomicAdd(slot + 3, n1); }
  }
}

// ---------------------------------------------------------------
// 4) Finalize: reduce NSLOT slots, total = sum_c loss_c/max(cnt_c,1)
// ---------------------------------------------------------------
__global__ void finalize_kernel(const float* __restrict__ accum,
                                float* __restrict__ out) {
  float l0 = 0.f, n0 = 0.f, l1 = 0.f, n1 = 0.f;
  for (int i = 0; i < NSLOT; i++) {
    l0 += accum[i * 4 + 0];
    n0 += accum[i * 4 + 1];
    l1 += accum[i * 4 + 2];
    n1 += accum[i * 4 + 3];
  }
  out[0] = l0 / fmaxf(n0, 1.0f) + l1 / fmaxf(n1, 1.0f);
}

extern "C" void kernel_launch(void* const* d_in, const int* in_sizes, int n_in,
                              void* d_out, int out_size, void* d_ws, size_t ws_size,
                              hipStream_t stream) {
  const float* er = (const float*)d_in[0];         // [B,C,H,W]
  const float* seg_logit = (const float*)d_in[1];  // [B,2,H,W]
  const int* seg_label = (const int*)d_in[2];      // [B,H,W]
  const int* gtb = (const int*)d_in[3];            // [B,H,W]
  float* out = (float*)d_out;

  // Workspace layout
  char* ws = (char*)d_ws;
  float* accum = (float*)ws;                         // NSLOT*4 floats
  const size_t ACC_BYTES = NSLOT * 4 * sizeof(float);
  int* pred = (int*)(ws + ACC_BYTES);                // NPIX ints
  float* nrm = (float*)(ws + ACC_BYTES + NPIX * 4);  // NPIX floats
  float* featT = (float*)(ws + ACC_BYTES + NPIX * 8);  // NPIX*C floats (~18.9MB)

  hipMemsetAsync(d_ws, 0, ACC_BYTES, stream);

  dim3 tb(32, 8, 1);
  dim3 tg(HWc / 32, Cc / 32, Bc);  // 288 x 8 x 2
  transpose_kernel<<<tg, tb, 0, stream>>>(er, featT);

  const int nblocks = (NPIX * 64) / 256;  // 4608, one wave per pixel
  prep_kernel<<<nblocks, 256, 0, stream>>>(featT, seg_logit, nrm, pred);
  loss_kernel<<<nblocks, 256, 0, stream>>>(featT, nrm, pred, seg_label, gtb, accum);
  finalize_kernel<<<1, 1, 0, stream>>>(accum, out);
}

// Round 3
// 56.670 us; speedup vs baseline: 4.7315x; 1.6651x over previous
//
#include <hip/hip_runtime.h>
#include <math.h>

// Problem constants (match reference setup_inputs)
#define Hc 96
#define Wc 96
#define Bc 2
#define Cc 256            // channels
#define HWc (Hc * Wc)     // 9216
#define NKc 25            // 5x5 neighborhood
#define NPIX (Bc * HWc)   // 18432
#define NSLOT 32          // spread accumulation slots

// Workspace byte offsets
#define OFF_ACC 0                       // NSLOT*2 floats (heavy loss per class)
#define OFF_CNT (NSLOT * 2 * 4)         // 2 floats: contributing count per class
#define OFF_MIS (OFF_CNT + 8)           // 2 floats: mispredicted count per class
#define OFF_HC (OFF_MIS + 8)            // 1 uint: heavy worklist count
#define OFF_NRM2 320                    // NPIX floats: sum of squares per pixel
#define OFF_PRED (OFF_NRM2 + NPIX * 4)  // NPIX ints
#define OFF_WL (OFF_PRED + NPIX * 4)    // NPIX uint4 worklist
#define OFF_FT (OFF_WL + NPIX * 16)     // NPIX*Cc floats featT
#define ZERO_BYTES (OFF_NRM2 + NPIX * 4)

__device__ __forceinline__ float wave_reduce_sum(float v) {
#pragma unroll
  for (int off = 32; off > 0; off >>= 1) v += __shfl_xor(v, off);
  return v;
}

// ---------------------------------------------------------------
// 1) Transpose er_input [B,C,HW] -> featT [B,HW,C], fused with
//    per-pixel sum-of-squares partials and pred (argmax of 2 logits).
// ---------------------------------------------------------------
__global__ __launch_bounds__(256) void transpose_kernel(
    const float* __restrict__ in, const float* __restrict__ seg_logit,
    float* __restrict__ out, float* __restrict__ nrm2, int* __restrict__ pred) {
  __shared__ float tile[32][33];
  __shared__ float part[8][32];
  const int bx = blockIdx.x;  // HW/32 = 288
  const int by = blockIdx.y;  // C/32  = 8
  const int b = blockIdx.z;
  const float* src = in + (size_t)b * Cc * HWc;
  float* dst = out + (size_t)b * HWc * Cc;
  const int tx = threadIdx.x;  // 0..31
  const int ty = threadIdx.y;  // 0..7
  const int p0 = bx * 32, c0 = by * 32;
#pragma unroll
  for (int i = 0; i < 4; i++)
    tile[ty + i * 8][tx] = src[(size_t)(c0 + ty + i * 8) * HWc + p0 + tx];
  __syncthreads();
#pragma unroll
  for (int i = 0; i < 4; i++)
    dst[(size_t)(p0 + ty + i * 8) * Cc + c0 + tx] = tile[tx][ty + i * 8];
  // per-pixel sum of squares over this 32-channel slice
  float s = 0.f;
#pragma unroll
  for (int i = 0; i < 4; i++) {
    float v = tile[ty * 4 + i][tx];
    s += v * v;
  }
  part[ty][tx] = s;
  __syncthreads();
  if (ty == 0) {
    float t = 0.f;
#pragma unroll
    for (int j = 0; j < 8; j++) t += part[j][tx];
    atomicAdd(&nrm2[b * HWc + p0 + tx], t);
    if (by == 0) {
      const int hw = p0 + tx;
      const float l0 = seg_logit[(size_t)(b * 2 + 0) * HWc + hw];
      const float l1 = seg_logit[(size_t)(b * 2 + 1) * HWc + hw];
      pred[b * HWc + hw] = (l1 > l0) ? 1 : 0;
    }
  }
}

// ---------------------------------------------------------------
// 2) Classify: 1 thread per pixel. Counts contributing / mispredicted
//    pixels per class; compacts heavy pixels (pred==c) into worklist
//    with precomputed neighbor-correctness masks.
// ---------------------------------------------------------------
__global__ __launch_bounds__(256) void classify_kernel(
    const int* __restrict__ label, const int* __restrict__ gtb,
    const int* __restrict__ pred, const float* __restrict__ nrm2,
    float* __restrict__ cnt, float* __restrict__ mis,
    unsigned int* __restrict__ heavyCount, uint4* __restrict__ worklist) {
  __shared__ unsigned int s_cnt[4];  // cnt0, cnt1, mis0, mis1
  if (threadIdx.x < 4) s_cnt[threadIdx.x] = 0;
  __syncthreads();
  const int tid = blockIdx.x * 256 + threadIdx.x;  // < NPIX
  bool heavy = false;
  int c = 0;
  unsigned mNow = 0, mNeg = 0;
  float a_norm = 0.f;
  {
    const int hw = tid % HWc;
    const int h = hw / Wc, w = hw % Wc;
    int g = gtb[tid];
    if (g == 255) g = 0;
    if (g) {  // boundary pixel
      c = label[tid];
      const int oc = 1 - c;
      const int pc = pred[tid];
      int count = 0;
#pragma unroll
      for (int k = 0; k < NKc; k++) {
        const int di = k / 5 - 2, dj = k % 5 - 2;
        const int hh = h + di, ww = w + dj;
        const bool inb = (hh >= 0) && (hh < Hc) && (ww >= 0) && (ww < Wc);
        int lb = 0, pr = 0;
        if (inb) {
          const int n = tid + di * Wc + dj;
          lb = label[n];
          pr = pred[n];
        }
        count += (lb == c);  // zero-pad: OOB counts as label 0
        if (inb) {
          if (lb == c && pr == c) mNow |= 1u << k;
          if (lb == oc && pr == oc) mNeg |= 1u << k;
        }
        // OOB with oc==0 would have w_neg=2 but feat=0,norm=0 -> neg_cos=0,
        // identical to the logit-0 case: safe to leave bit unset.
      }
      count -= 1;  // exclude center (always label==c)
      if (count >= 1) {  // contributing pixel
        atomicAdd(&s_cnt[c], 1u);
        if (pc == c) {
          heavy = true;
          a_norm = sqrtf(nrm2[tid]);
        } else {
          atomicAdd(&s_cnt[2 + c], 1u);  // constant log(26) loss
        }
      }
    }
  }
  // wave-aggregated worklist append
  const unsigned long long m = __ballot(heavy);
  const int lane = threadIdx.x & 63;
  if (m) {
    unsigned int base = 0;
    if (lane == 0) base = atomicAdd(heavyCount, (unsigned)__popcll(m));
    base = __shfl(base, 0);
    if (heavy) {
      const unsigned idx = base + (unsigned)__popcll(m & ((1ull << lane) - 1ull));
      worklist[idx] = make_uint4((unsigned)tid | ((unsigned)c << 16), mNow, mNeg,
                                 __float_as_uint(a_norm));
    }
  }
  __syncthreads();
  if (threadIdx.x < 2) {
    if (s_cnt[threadIdx.x]) atomicAdd(&cnt[threadIdx.x], (float)s_cnt[threadIdx.x]);
    if (s_cnt[2 + threadIdx.x]) atomicAdd(&mis[threadIdx.x], (float)s_cnt[2 + threadIdx.x]);
  }
}

// ---------------------------------------------------------------
// 3) Heavy: one wave per worklist entry (grid-stride).
// ---------------------------------------------------------------
__global__ __launch_bounds__(256) void heavy_kernel(
    const float* __restrict__ featT, const float* __restrict__ nrm2,
    const unsigned int* __restrict__ heavyCount,
    const uint4* __restrict__ worklist, float* __restrict__ accum) {
  __shared__ float s_loss[2];
  if (threadIdx.x < 2) s_loss[threadIdx.x] = 0.f;
  __syncthreads();
  const int lane = threadIdx.x & 63;
  const int wv = threadIdx.x >> 6;
  const unsigned nH = *heavyCount;
  const unsigned nw = gridDim.x * 4;
  const float4* fp = (const float4*)featT;
  float lacc0 = 0.f, lacc1 = 0.f;
  for (unsigned i = blockIdx.x * 4 + wv; i < nH; i += nw) {
    const uint4 e = worklist[i];
    const int wid = e.x & 0xffff;
    const int c = (e.x >> 16) & 1;
    const unsigned mNow = e.y, mNeg = e.z;
    const float a_norm = __uint_as_float(e.w);

    // neighbor norms (only mNeg lanes; mask bit guarantees in-bounds)
    float nkv = 0.f;
    if (lane < NKc && ((mNeg >> lane) & 1u))
      nkv = sqrtf(nrm2[wid + (lane / 5 - 2) * Wc + (lane % 5 - 2)]);

    const float4 anchor = fp[(size_t)wid * 64 + lane];
    float4 pos = make_float4(0.f, 0.f, 0.f, 0.f);
    float dpart[NKc];
    const unsigned mAny = mNow | mNeg;
#pragma unroll
    for (int k = 0; k < NKc; k++) {
      dpart[k] = 0.f;
      if ((mAny >> k) & 1u) {  // wave-uniform
        const int off = wid + (k / 5 - 2) * Wc + (k % 5 - 2);
        const float4 f = fp[(size_t)off * 64 + lane];
        if ((mNow >> k) & 1u) {
          pos.x += f.x; pos.y += f.y; pos.z += f.z; pos.w += f.w;
        }
        if ((mNeg >> k) & 1u)
          dpart[k] = anchor.x * f.x + anchor.y * f.y + anchor.z * f.z + anchor.w * f.w;
      }
    }
    float4 pv;
    pv.x = (pos.x - anchor.x) * (1.0f / 25.0f);
    pv.y = (pos.y - anchor.y) * (1.0f / 25.0f);
    pv.z = (pos.z - anchor.z) * (1.0f / 25.0f);
    pv.w = (pos.w - anchor.w) * (1.0f / 25.0f);
    const float p2 = wave_reduce_sum(pv.x * pv.x + pv.y * pv.y + pv.z * pv.z + pv.w * pv.w);
    const float ad = wave_reduce_sum(anchor.x * pv.x + anchor.y * pv.y +
                                     anchor.z * pv.z + anchor.w * pv.w);
    const float x0 = (ad / (a_norm * sqrtf(p2) + 1e-8f)) * 10.0f;
    float mx = fmaxf(x0, 0.f);  // >=1 zero-logit always present (center)
#pragma unroll
    for (int k = 0; k < NKc; k++) {
      if ((mNeg >> k) & 1u) {
        const float d = wave_reduce_sum(dpart[k]);
        const float nk = __shfl(nkv, k);
        dpart[k] = ((d * 2.0f) / (a_norm * nk * 2.0f + 1e-8f)) * 10.0f;
        mx = fmaxf(mx, dpart[k]);
      }
    }
    float s = expf(x0 - mx) + (float)(NKc - __popc(mNeg)) * expf(-mx);
#pragma unroll
    for (int k = 0; k < NKc; k++)
      if ((mNeg >> k) & 1u) s += expf(dpart[k] - mx);
    const float loss = mx + logf(s) - x0;
    if (lane == 0) {
      if (c == 0) lacc0 += loss; else lacc1 += loss;
    }
  }
  if (lane == 0) {
    if (lacc0 != 0.f) atomicAdd(&s_loss[0], lacc0);
    if (lacc1 != 0.f) atomicAdd(&s_loss[1], lacc1);
  }
  __syncthreads();
  if (threadIdx.x < 2) {
    const float v = s_loss[threadIdx.x];
    if (v != 0.f) atomicAdd(&accum[(blockIdx.x & (NSLOT - 1)) * 2 + threadIdx.x], v);
  }
}

// ---------------------------------------------------------------
// 4) Finalize
// ---------------------------------------------------------------
__global__ void finalize_kernel(const float* __restrict__ accum,
                                const float* __restrict__ cnt,
                                const float* __restrict__ mis,
                                float* __restrict__ out) {
  float L0 = 0.f, L1 = 0.f;
  for (int i = 0; i < NSLOT; i++) {
    L0 += accum[i * 2 + 0];
    L1 += accum[i * 2 + 1];
  }
  const float LOG26 = logf(26.0f);
  out[0] = (L0 + LOG26 * mis[0]) / fmaxf(cnt[0], 1.0f) +
           (L1 + LOG26 * mis[1]) / fmaxf(cnt[1], 1.0f);
}

extern "C" void kernel_launch(void* const* d_in, const int* in_sizes, int n_in,
                              void* d_out, int out_size, void* d_ws, size_t ws_size,
                              hipStream_t stream) {
  const float* er = (const float*)d_in[0];         // [B,C,H,W]
  const float* seg_logit = (const float*)d_in[1];  // [B,2,H,W]
  const int* seg_label = (const int*)d_in[2];      // [B,H,W]
  const int* gtb = (const int*)d_in[3];            // [B,H,W]
  float* out = (float*)d_out;

  char* ws = (char*)d_ws;
  float* accum = (float*)(ws + OFF_ACC);
  float* cnt = (float*)(ws + OFF_CNT);
  float* mis = (float*)(ws + OFF_MIS);
  unsigned int* heavyCount = (unsigned int*)(ws + OFF_HC);
  float* nrm2 = (float*)(ws + OFF_NRM2);
  int* pred = (int*)(ws + OFF_PRED);
  uint4* worklist = (uint4*)(ws + OFF_WL);
  float* featT = (float*)(ws + OFF_FT);

  hipMemsetAsync(d_ws, 0, ZERO_BYTES, stream);

  dim3 tb(32, 8, 1);
  dim3 tg(HWc / 32, Cc / 32, Bc);  // 288 x 8 x 2
  transpose_kernel<<<tg, tb, 0, stream>>>(er, seg_logit, featT, nrm2, pred);

  classify_kernel<<<NPIX / 256, 256, 0, stream>>>(seg_label, gtb, pred, nrm2,
                                                  cnt, mis, heavyCount, worklist);

  heavy_kernel<<<1152, 256, 0, stream>>>(featT, nrm2, heavyCount, worklist, accum);

  finalize_kernel<<<1, 1, 0, stream>>>(accum, cnt, mis, out);
}

// Round 4
// 51.820 us; speedup vs baseline: 5.1743x; 1.0936x over previous
//
#include <hip/hip_runtime.h>
#include <math.h>

// Problem constants (match reference setup_inputs)
#define Hc 96
#define Wc 96
#define Bc 2
#define Cc 256            // channels
#define HWc (Hc * Wc)     // 9216
#define NKc 25            // 5x5 neighborhood
#define NPIX (Bc * HWc)   // 18432
#define NSLOT 32          // spread accumulation slots

// Workspace byte offsets
#define OFF_ACC 0                       // NSLOT*2 floats (heavy loss per class)
#define OFF_CNT (NSLOT * 2 * 4)         // 2 floats: contributing count per class
#define OFF_MIS (OFF_CNT + 8)           // 2 floats: mispredicted count per class
#define OFF_HC (OFF_MIS + 8)            // 1 uint: heavy worklist count
#define HDR_FLOATS 80                   // first 320 B zeroed by transpose blk 0
#define OFF_NRM2 320                    // NPIX floats: sum of squares per pixel
#define OFF_PRED (OFF_NRM2 + NPIX * 4)  // NPIX ints
#define OFF_WL (OFF_PRED + NPIX * 4)    // NPIX uint4 worklist
#define OFF_FT (OFF_WL + NPIX * 16)     // NPIX*Cc floats featT

__device__ __forceinline__ float wave_reduce_sum(float v) {
#pragma unroll
  for (int off = 32; off > 0; off >>= 1) v += __shfl_xor(v, off);
  return v;
}

// ---------------------------------------------------------------
// 1) Transpose er_input [B,C,HW] -> featT [B,HW,C].  Each block owns
//    a 32-pixel tile and loops all 8 channel slices, so per-pixel
//    sum-of-squares completes in-block (plain store, no atomics, no
//    pre-zeroed workspace).  Also computes pred and zeroes the
//    320-byte accumulator header (block 0).
// ---------------------------------------------------------------
__global__ __launch_bounds__(256) void transpose_kernel(
    const float* __restrict__ in, const float* __restrict__ seg_logit,
    float* __restrict__ out, float* __restrict__ nrm2, int* __restrict__ pred,
    float* __restrict__ hdr) {
  __shared__ float tile[32][33];
  __shared__ float part[8][32];
  const int bx = blockIdx.x;  // 0..287 pixel tile
  const int b = blockIdx.y;   // batch
  const int tx = threadIdx.x;  // 0..31
  const int ty = threadIdx.y;  // 0..7
  const float* src = in + (size_t)b * Cc * HWc;
  float* dst = out + (size_t)b * HWc * Cc;
  const int p0 = bx * 32;

  if (bx == 0 && b == 0) {
    const int t = ty * 32 + tx;
    if (t < HDR_FLOATS) hdr[t] = 0.f;
  }

  float psum = 0.f;
  for (int by = 0; by < 8; ++by) {
    const int c0 = by * 32;
#pragma unroll
    for (int i = 0; i < 4; i++)
      tile[ty + i * 8][tx] = src[(size_t)(c0 + ty + i * 8) * HWc + p0 + tx];
    __syncthreads();
#pragma unroll
    for (int i = 0; i < 4; i++)
      dst[(size_t)(p0 + ty + i * 8) * Cc + c0 + tx] = tile[tx][ty + i * 8];
    // thread (tx,ty) accumulates channels ty*4..ty*4+3 of pixel p0+tx
#pragma unroll
    for (int i = 0; i < 4; i++) {
      const float v = tile[ty * 4 + i][tx];
      psum += v * v;
    }
    __syncthreads();
  }
  part[ty][tx] = psum;
  __syncthreads();
  if (ty == 0) {
    float t = 0.f;
#pragma unroll
    for (int j = 0; j < 8; j++) t += part[j][tx];
    const int hw = p0 + tx;
    nrm2[b * HWc + hw] = t;
    const float l0 = seg_logit[(size_t)(b * 2 + 0) * HWc + hw];
    const float l1 = seg_logit[(size_t)(b * 2 + 1) * HWc + hw];
    pred[b * HWc + hw] = (l1 > l0) ? 1 : 0;
  }
}

// ---------------------------------------------------------------
// 2) Classify: 1 thread per pixel. Counts contributing / mispredicted
//    pixels per class; compacts heavy pixels (pred==c) into worklist
//    with precomputed neighbor-correctness masks.
// ---------------------------------------------------------------
__global__ __launch_bounds__(256) void classify_kernel(
    const int* __restrict__ label, const int* __restrict__ gtb,
    const int* __restrict__ pred, const float* __restrict__ nrm2,
    float* __restrict__ cnt, float* __restrict__ mis,
    unsigned int* __restrict__ heavyCount, uint4* __restrict__ worklist) {
  __shared__ unsigned int s_cnt[4];  // cnt0, cnt1, mis0, mis1
  if (threadIdx.x < 4) s_cnt[threadIdx.x] = 0;
  __syncthreads();
  const int tid = blockIdx.x * 256 + threadIdx.x;  // < NPIX
  bool heavy = false;
  int c = 0;
  unsigned mNow = 0, mNeg = 0;
  float a_norm = 0.f;
  {
    const int hw = tid % HWc;
    const int h = hw / Wc, w = hw % Wc;
    int g = gtb[tid];
    if (g == 255) g = 0;
    if (g) {  // boundary pixel
      c = label[tid];
      const int oc = 1 - c;
      const int pc = pred[tid];
      int count = 0;
#pragma unroll
      for (int k = 0; k < NKc; k++) {
        const int di = k / 5 - 2, dj = k % 5 - 2;
        const int hh = h + di, ww = w + dj;
        const bool inb = (hh >= 0) && (hh < Hc) && (ww >= 0) && (ww < Wc);
        int lb = 0, pr = 0;
        if (inb) {
          const int n = tid + di * Wc + dj;
          lb = label[n];
          pr = pred[n];
        }
        count += (lb == c);  // zero-pad: OOB counts as label 0
        if (inb) {
          if (lb == c && pr == c) mNow |= 1u << k;
          if (lb == oc && pr == oc) mNeg |= 1u << k;
        }
        // OOB with oc==0 has w_neg=2 but feat=0,norm=0 -> neg_cos=0, identical
        // to the zero-logit bucket: safe to leave both bits unset.
      }
      count -= 1;  // exclude center (always label==c)
      if (count >= 1) {  // contributing pixel
        atomicAdd(&s_cnt[c], 1u);
        if (pc == c) {
          heavy = true;
          a_norm = sqrtf(nrm2[tid]);
        } else {
          atomicAdd(&s_cnt[2 + c], 1u);  // constant log(26) loss
        }
      }
    }
  }
  // wave-aggregated worklist append
  const unsigned long long m = __ballot(heavy);
  const int lane = threadIdx.x & 63;
  if (m) {
    unsigned int base = 0;
    if (lane == 0) base = atomicAdd(heavyCount, (unsigned)__popcll(m));
    base = __shfl(base, 0);
    if (heavy) {
      const unsigned idx = base + (unsigned)__popcll(m & ((1ull << lane) - 1ull));
      worklist[idx] = make_uint4((unsigned)tid | ((unsigned)c << 16), mNow, mNeg,
                                 __float_as_uint(a_norm));
    }
  }
  __syncthreads();
  if (threadIdx.x < 2) {
    if (s_cnt[threadIdx.x]) atomicAdd(&cnt[threadIdx.x], (float)s_cnt[threadIdx.x]);
    if (s_cnt[2 + threadIdx.x]) atomicAdd(&mis[threadIdx.x], (float)s_cnt[2 + threadIdx.x]);
  }
}

// ---------------------------------------------------------------
// 3) Heavy: one wave per worklist entry (grid-stride).
// ---------------------------------------------------------------
__global__ __launch_bounds__(256) void heavy_kernel(
    const float* __restrict__ featT, const float* __restrict__ nrm2,
    const unsigned int* __restrict__ heavyCount,
    const uint4* __restrict__ worklist, float* __restrict__ accum) {
  __shared__ float s_loss[2];
  if (threadIdx.x < 2) s_loss[threadIdx.x] = 0.f;
  __syncthreads();
  const int lane = threadIdx.x & 63;
  const int wv = threadIdx.x >> 6;
  const unsigned nH = *heavyCount;
  const unsigned nw = gridDim.x * 4;
  const float4* fp = (const float4*)featT;
  float lacc0 = 0.f, lacc1 = 0.f;
  for (unsigned i = blockIdx.x * 4 + wv; i < nH; i += nw) {
    const uint4 e = worklist[i];
    const int wid = e.x & 0xffff;
    const int c = (e.x >> 16) & 1;
    const unsigned mNow = e.y, mNeg = e.z;
    const float a_norm = __uint_as_float(e.w);

    // neighbor norms (only mNeg lanes; mask bit guarantees in-bounds)
    float nkv = 0.f;
    if (lane < NKc && ((mNeg >> lane) & 1u))
      nkv = sqrtf(nrm2[wid + (lane / 5 - 2) * Wc + (lane % 5 - 2)]);

    const float4 anchor = fp[(size_t)wid * 64 + lane];
    float4 pos = make_float4(0.f, 0.f, 0.f, 0.f);
    float dpart[NKc];
    const unsigned mAny = mNow | mNeg;
#pragma unroll
    for (int k = 0; k < NKc; k++) {
      dpart[k] = 0.f;
      if ((mAny >> k) & 1u) {  // wave-uniform
        const int off = wid + (k / 5 - 2) * Wc + (k % 5 - 2);
        const float4 f = fp[(size_t)off * 64 + lane];
        if ((mNow >> k) & 1u) {
          pos.x += f.x; pos.y += f.y; pos.z += f.z; pos.w += f.w;
        }
        if ((mNeg >> k) & 1u)
          dpart[k] = anchor.x * f.x + anchor.y * f.y + anchor.z * f.z + anchor.w * f.w;
      }
    }
    float4 pv;
    pv.x = (pos.x - anchor.x) * (1.0f / 25.0f);
    pv.y = (pos.y - anchor.y) * (1.0f / 25.0f);
    pv.z = (pos.z - anchor.z) * (1.0f / 25.0f);
    pv.w = (pos.w - anchor.w) * (1.0f / 25.0f);
    const float p2 = wave_reduce_sum(pv.x * pv.x + pv.y * pv.y + pv.z * pv.z + pv.w * pv.w);
    const float ad = wave_reduce_sum(anchor.x * pv.x + anchor.y * pv.y +
                                     anchor.z * pv.z + anchor.w * pv.w);
    const float x0 = (ad / (a_norm * sqrtf(p2) + 1e-8f)) * 10.0f;
    float mx = fmaxf(x0, 0.f);  // >=1 zero-logit always present (center)
#pragma unroll
    for (int k = 0; k < NKc; k++) {
      if ((mNeg >> k) & 1u) {
        const float d = wave_reduce_sum(dpart[k]);
        const float nk = __shfl(nkv, k);
        dpart[k] = ((d * 2.0f) / (a_norm * nk * 2.0f + 1e-8f)) * 10.0f;
        mx = fmaxf(mx, dpart[k]);
      }
    }
    float s = expf(x0 - mx) + (float)(NKc - __popc(mNeg)) * expf(-mx);
#pragma unroll
    for (int k = 0; k < NKc; k++)
      if ((mNeg >> k) & 1u) s += expf(dpart[k] - mx);
    const float loss = mx + logf(s) - x0;
    if (lane == 0) {
      if (c == 0) lacc0 += loss; else lacc1 += loss;
    }
  }
  if (lane == 0) {
    if (lacc0 != 0.f) atomicAdd(&s_loss[0], lacc0);
    if (lacc1 != 0.f) atomicAdd(&s_loss[1], lacc1);
  }
  __syncthreads();
  if (threadIdx.x < 2) {
    const float v = s_loss[threadIdx.x];
    if (v != 0.f) atomicAdd(&accum[(blockIdx.x & (NSLOT - 1)) * 2 + threadIdx.x], v);
  }
}

// ---------------------------------------------------------------
// 4) Finalize (one wave): reduce NSLOT slots per class.
// ---------------------------------------------------------------
__global__ void finalize_kernel(const float* __restrict__ accum,
                                const float* __restrict__ cnt,
                                const float* __restrict__ mis,
                                float* __restrict__ out) {
  const int lane = threadIdx.x;
  float l0 = 0.f, l1 = 0.f;
  if (lane < NSLOT) {
    l0 = accum[lane * 2 + 0];
    l1 = accum[lane * 2 + 1];
  }
  l0 = wave_reduce_sum(l0);
  l1 = wave_reduce_sum(l1);
  if (lane == 0) {
    const float LOG26 = logf(26.0f);
    out[0] = (l0 + LOG26 * mis[0]) / fmaxf(cnt[0], 1.0f) +
             (l1 + LOG26 * mis[1]) / fmaxf(cnt[1], 1.0f);
  }
}

extern "C" void kernel_launch(void* const* d_in, const int* in_sizes, int n_in,
                              void* d_out, int out_size, void* d_ws, size_t ws_size,
                              hipStream_t stream) {
  const float* er = (const float*)d_in[0];         // [B,C,H,W]
  const float* seg_logit = (const float*)d_in[1];  // [B,2,H,W]
  const int* seg_label = (const int*)d_in[2];      // [B,H,W]
  const int* gtb = (const int*)d_in[3];            // [B,H,W]
  float* out = (float*)d_out;

  char* ws = (char*)d_ws;
  float* hdr = (float*)ws;  // first 320 B: accum/cnt/mis/heavyCount
  float* accum = (float*)(ws + OFF_ACC);
  float* cnt = (float*)(ws + OFF_CNT);
  float* mis = (float*)(ws + OFF_MIS);
  unsigned int* heavyCount = (unsigned int*)(ws + OFF_HC);
  float* nrm2 = (float*)(ws + OFF_NRM2);
  int* pred = (int*)(ws + OFF_PRED);
  uint4* worklist = (uint4*)(ws + OFF_WL);
  float* featT = (float*)(ws + OFF_FT);

  dim3 tb(32, 8, 1);
  dim3 tg(HWc / 32, Bc, 1);  // 288 x 2, each block loops 8 channel slices
  transpose_kernel<<<tg, tb, 0, stream>>>(er, seg_logit, featT, nrm2, pred, hdr);

  classify_kernel<<<NPIX / 256, 256, 0, stream>>>(seg_label, gtb, pred, nrm2,
                                                  cnt, mis, heavyCount, worklist);

  heavy_kernel<<<1152, 256, 0, stream>>>(featT, nrm2, heavyCount, worklist, accum);

  finalize_kernel<<<1, 64, 0, stream>>>(accum, cnt, mis, out);
}